// Round 1
// 243.163 us; speedup vs baseline: 1.0228x; 1.0228x over previous
//
#include <hip/hip_runtime.h>
#include <stdint.h>

#define NE 4096
#define FD 512
#define NCELLS 39
#define NPAIRS 8192
#define NT (FD / 64)  // 8 K-tiles of BK=64

typedef __attribute__((ext_vector_type(8))) short short8;
typedef __attribute__((ext_vector_type(8))) unsigned short ushort8;
typedef __attribute__((ext_vector_type(4))) float f32x4;
typedef __attribute__((ext_vector_type(4))) unsigned int uint4v;

__device__ __forceinline__ unsigned short f2bf(float f) {
  union { float f; uint32_t u; } v; v.f = f;
  uint32_t u = v.u;
  return (unsigned short)((u + 0x7fffu + ((u >> 16) & 1u)) >> 16);  // RNE
}
__device__ __forceinline__ float bf2f(unsigned short b) {
  return __uint_as_float(((uint32_t)b) << 16);
}

__device__ __forceinline__ void async16(const void* g, void* l) {
  __builtin_amdgcn_global_load_lds((const __attribute__((address_space(1))) void*)g,
                                   (__attribute__((address_space(3))) void*)l, 16, 0, 0);
}

// ---- kernel 1: embedding fp32 -> bf16 ----
__global__ __launch_bounds__(256) void conv_e(const float* __restrict__ E,
                                              unsigned short* __restrict__ Ebf) {
  const int i = blockIdx.x * 256 + threadIdx.x;
  const float4 v = ((const float4*)E)[i];
  ushort4 o;
  o.x = f2bf(v.x); o.y = f2bf(v.y); o.z = f2bf(v.z); o.w = f2bf(v.w);
  ((ushort4*)Ebf)[i] = o;
}

// ---- kernel 2: Wt[ci][k][n] = wl[c,n] * wl[c,k] * W[n,k], bf16, transposed ----
__global__ __launch_bounds__(256) void prep_w(const float* __restrict__ W,
                                              const float* __restrict__ wl,
                                              unsigned short* __restrict__ Wt,
                                              int c0) {
  __shared__ float tile[32][33];
  const int ci = blockIdx.z;
  const int tn = blockIdx.x * 32, tk = blockIdx.y * 32;
  const int tx = threadIdx.x & 31, ty = threadIdx.x >> 5;
  const float* wlr = wl + (size_t)(c0 + ci) * FD;
#pragma unroll
  for (int i = 0; i < 4; i++) {
    int n = tn + ty + i * 8;
    tile[ty + i * 8][tx] = W[(size_t)n * FD + tk + tx] * wlr[n];
  }
  __syncthreads();
  unsigned short* dst = Wt + (size_t)ci * FD * FD;
#pragma unroll
  for (int i = 0; i < 4; i++) {
    int kout = tk + ty + i * 8;
    dst[(size_t)kout * FD + tn + tx] = f2bf(tile[tx][ty + i * 8] * wlr[kout]);
  }
}

// ---- kernel 3: U[ci][e][k] = sum_n Ebf[e,n] * Wt[ci][k][n]  (bf16 out) ----
// 256x256 8-phase template (T1+T2+T3+T4+T5): BK=64, 8 waves (2Mx4N), 128KiB LDS
// double-buffer, XOR-swizzled granules (both sides: pre-swizzled global source
// + swizzled ds_read), counted vmcnt(4) at phases 4/8 only, setprio around MFMA.
__global__ __launch_bounds__(512, 2) void gemm_k(const unsigned short* __restrict__ Ebf,
                                                 const unsigned short* __restrict__ Wt,
                                                 unsigned short* __restrict__ U) {
  __shared__ unsigned short lds[2][2][2][128 * 64];  // [buf][A=0/B=1][half][row*64+col]
  const int t = threadIdx.x;
  const int nwg = gridDim.x;
  const int id = blockIdx.x;
  // XCD-aware bijective swizzle (nwg % 8 == 0 always: nwg = 32*g)
  const int fid = (id & 7) * (nwg >> 3) + (id >> 3);
  const int bx = fid & 15;          // 16 row-blocks of 256 entities
  const int by = (fid >> 4) & 1;    // 2 col-blocks of 256 k
  const int ci = fid >> 5;          // cell

  const unsigned short* Ag = Ebf + (size_t)bx * 256 * FD;
  const unsigned short* Bg = Wt + (size_t)ci * FD * FD + (size_t)by * 256 * FD;

  const int wave = t >> 6, lane = t & 63;
  const int wm = wave >> 2, wn = wave & 3;  // 2M x 4N wave grid
  const int lr = lane & 15, lq = lane >> 4;

  // staging: physical granule pg (row=pg>>3, g=pg&7); source uses g ^ (row&7)
  const int pg0 = t, pg1 = 512 + t;
  const int sr0 = pg0 >> 3, sg0 = pg0 & 7;
  const int sr1 = pg1 >> 3, sg1 = pg1 & 7;
  const int soff0 = sr0 * FD + ((sg0 ^ (sr0 & 7)) << 3);
  const int soff1 = sr1 * FD + ((sg1 ^ (sr1 & 7)) << 3);
  const int loff0 = pg0 * 8, loff1 = pg1 * 8;

  // read swizzle: frag rows always have row%8 == lr%8
  const int swz0 = (lq ^ (lr & 7)) << 3;        // k-slice 0 granule
  const int swz1 = ((4 + lq) ^ (lr & 7)) << 3;  // k-slice 1 granule

#define STAGE(OP, HALF, KT, GBASE)                                                \
  do {                                                                            \
    const int bi_ = (KT) & 1;             /* buffer from UNclamped kt */          \
    const int kt_ = (KT) < NT ? (KT) : (NT - 1); /* clamp src, keep count */      \
    const unsigned short* gb_ = (GBASE) + (size_t)(HALF) * (128 * FD) + kt_ * 64; \
    unsigned short* d_ = &lds[bi_][OP][HALF][0];                                  \
    async16(gb_ + soff0, d_ + loff0);                                             \
    async16(gb_ + soff1, d_ + loff1);                                             \
  } while (0)

  short8 a[8], b01[4], b23[4];
  f32x4 acc[8][4];
#pragma unroll
  for (int i = 0; i < 8; i++)
#pragma unroll
    for (int j = 0; j < 4; j++) acc[i][j] = (f32x4){0.f, 0.f, 0.f, 0.f};

#define LDA(BUF, MSET)                                                  \
  do {                                                                  \
    const unsigned short* p_ = &lds[BUF][0][wm][0];                     \
    _Pragma("unroll") for (int mi_ = 0; mi_ < 4; ++mi_) {               \
      const int row_ = (MSET) * 64 + mi_ * 16 + lr;                     \
      a[mi_ * 2 + 0] = *(const short8*)&p_[row_ * 64 + swz0];           \
      a[mi_ * 2 + 1] = *(const short8*)&p_[row_ * 64 + swz1];           \
    }                                                                   \
  } while (0)

#define LDB(BUF, NSET, DST)                                             \
  do {                                                                  \
    const unsigned short* p_ = &lds[BUF][1][wn >> 1][0];                \
    _Pragma("unroll") for (int ni_ = 0; ni_ < 2; ++ni_) {               \
      const int row_ = (wn & 1) * 64 + ((NSET) * 2 + ni_) * 16 + lr;    \
      (DST)[ni_ * 2 + 0] = *(const short8*)&p_[row_ * 64 + swz0];       \
      (DST)[ni_ * 2 + 1] = *(const short8*)&p_[row_ * 64 + swz1];       \
    }                                                                   \
  } while (0)

#define MMA(MSET, NSET, B)                                                               \
  do {                                                                                   \
    __builtin_amdgcn_s_setprio(1);                                                       \
    _Pragma("unroll") for (int mi_ = 0; mi_ < 4; ++mi_)                                  \
    _Pragma("unroll") for (int ni_ = 0; ni_ < 2; ++ni_)                                  \
    _Pragma("unroll") for (int s_ = 0; s_ < 2; ++s_)                                     \
      acc[(MSET) * 4 + mi_][(NSET) * 2 + ni_] = __builtin_amdgcn_mfma_f32_16x16x32_bf16( \
          a[mi_ * 2 + s_], (B)[ni_ * 2 + s_],                                            \
          acc[(MSET) * 4 + mi_][(NSET) * 2 + ni_], 0, 0, 0);                             \
    __builtin_amdgcn_s_setprio(0);                                                       \
  } while (0)

#define SYNC_LG()                                        \
  do {                                                   \
    __builtin_amdgcn_s_barrier();                        \
    asm volatile("s_waitcnt lgkmcnt(0)" ::: "memory");   \
  } while (0)

  // prologue: all 4 half-tiles of kt0 + B-lo,A-lo of kt1 (6 HTs = 12 loads)
  STAGE(1, 0, 0, Bg); STAGE(0, 0, 0, Ag); STAGE(1, 1, 0, Bg); STAGE(0, 1, 0, Ag);
  STAGE(1, 0, 1, Bg); STAGE(0, 0, 1, Ag);
  asm volatile("s_waitcnt vmcnt(4)" ::: "memory");  // kt0 fully landed
  __builtin_amdgcn_s_barrier();

  for (int it = 0; it < NT / 2; ++it) {
    const int k1 = 2 * it + 1, k2 = 2 * it + 2, k3 = 2 * it + 3;
    // ----- K-tile 2it from buf0 -----
    // ph1: Q(m0-3,n01); reads A03+Bn01 (12); stage B-hi(k1)->buf1
    LDA(0, 0); LDB(0, 0, b01);
    STAGE(1, 1, k1, Bg);
    SYNC_LG(); MMA(0, 0, b01); __builtin_amdgcn_s_barrier();
    // ph2: Q(m0-3,n23); reads Bn23 (4); stage A-hi(k1)->buf1
    LDB(0, 1, b23);
    STAGE(0, 1, k1, Ag);
    SYNC_LG(); MMA(0, 1, b23); __builtin_amdgcn_s_barrier();
    // ph3: Q(m4-7,n23); reads A47 (8); stage B-lo(k2)->buf0 (B reads of buf0 done ph2)
    LDA(0, 1);
    STAGE(1, 0, k2, Bg);
    SYNC_LG(); MMA(1, 1, b23); __builtin_amdgcn_s_barrier();
    // ph4: Q(m4-7,n01); no reads; stage A-lo(k2)->buf0 (A reads done ph3); counted vmcnt
    STAGE(0, 0, k2, Ag);
    __builtin_amdgcn_s_barrier();
    MMA(1, 0, b01);
    asm volatile("s_waitcnt vmcnt(4)" ::: "memory");  // kt1 fully landed
    __builtin_amdgcn_s_barrier();
    // ----- K-tile 2it+1 from buf1 -----
    // ph5: stage B-hi(k2)->buf0
    LDA(1, 0); LDB(1, 0, b01);
    STAGE(1, 1, k2, Bg);
    SYNC_LG(); MMA(0, 0, b01); __builtin_amdgcn_s_barrier();
    // ph6: stage A-hi(k2)->buf0
    LDB(1, 1, b23);
    STAGE(0, 1, k2, Ag);
    SYNC_LG(); MMA(0, 1, b23); __builtin_amdgcn_s_barrier();
    // ph7: stage B-lo(k3)->buf1 (B reads of buf1 done ph6)
    LDA(1, 1);
    STAGE(1, 0, k3, Bg);
    SYNC_LG(); MMA(1, 1, b23); __builtin_amdgcn_s_barrier();
    // ph8: stage A-lo(k3)->buf1 (A reads done ph7); counted vmcnt
    STAGE(0, 0, k3, Ag);
    __builtin_amdgcn_s_barrier();
    MMA(1, 0, b01);
    asm volatile("s_waitcnt vmcnt(4)" ::: "memory");  // kt2 fully landed
    __builtin_amdgcn_s_barrier();
  }

  // epilogue: C/D layout col=lane&15, row=(lane>>4)*4+reg
  unsigned short* Up = U + (size_t)ci * NE * FD;
  const int mrow0 = bx * 256 + wm * 128;
  const int ncol0 = by * 256 + wn * 64;
#pragma unroll
  for (int mi = 0; mi < 8; ++mi) {
    const int mbase = mrow0 + mi * 16 + lq * 4;
#pragma unroll
    for (int ni = 0; ni < 4; ++ni) {
      const int n = ncol0 + ni * 16 + lr;
#pragma unroll
      for (int r = 0; r < 4; ++r)
        Up[(size_t)(mbase + r) * FD + n] = f2bf(acc[mi][ni][r]);
    }
  }
#undef STAGE
#undef LDA
#undef LDB
#undef MMA
#undef SYNC_LG
}

// ---- kernel 4: out[c,p] = sum_k U[ci,i0,k] * Ebf[i1,k] ----
// Plain (cached) U loads: U was just written and fits in the 256MB L3.
// Transpose-butterfly reduce: 10 shuffles per 8-pair batch (was 48),
// identical reduction tree (xor 1,2,4 then 8,16,32).
__global__ __launch_bounds__(256) void dot_k(const unsigned short* __restrict__ U,
                                             const unsigned short* __restrict__ Ebf,
                                             const int* __restrict__ index,
                                             float* __restrict__ out,
                                             int c0) {
  const int ci = blockIdx.y;
  const int c = c0 + ci;
  const int wave = threadIdx.x >> 6, lane = threadIdx.x & 63;
  const unsigned short* Uc = U + (size_t)ci * NE * FD;
  const size_t cp = (size_t)c * NPAIRS;
  const int2* idx2 = (const int2*)index + cp;
  float* op = out + cp;
  const int pbase = (blockIdx.x * 4 + wave) * 32;

  const int b1 = lane & 1, b2 = (lane >> 1) & 1, b4 = (lane >> 2) & 1;

  for (int batch = 0; batch < 4; batch++) {
    const int pb = pbase + batch * 8;
    int2 id[8];
#pragma unroll
    for (int b = 0; b < 8; b++) id[b] = idx2[pb + b];
    uint4v uv[8], ev[8];
#pragma unroll
    for (int b = 0; b < 8; b++) {
      uv[b] = *(const uint4v*)(Uc + (size_t)id[b].x * FD + lane * 8);
      ev[b] = *(const uint4v*)(Ebf + (size_t)id[b].y * FD + lane * 8);
    }
    float v[8];
#pragma unroll
    for (int b = 0; b < 8; b++) {
      const ushort8 u = *(const ushort8*)&uv[b];
      const ushort8 e = *(const ushort8*)&ev[b];
      float s = 0.f;
#pragma unroll
      for (int q = 0; q < 8; q++) s += bf2f(u[q]) * bf2f(e[q]);
      v[b] = s;
    }
    // fold pair-index bit 0 into lane bit 0
    float w[4];
#pragma unroll
    for (int q = 0; q < 4; q++) {
      const float keep = b1 ? v[2 * q + 1] : v[2 * q];
      const float send = b1 ? v[2 * q] : v[2 * q + 1];
      w[q] = keep + __shfl_xor(send, 1, 64);
    }
    // bit 1
    float u2[2];
#pragma unroll
    for (int q = 0; q < 2; q++) {
      const float keep = b2 ? w[2 * q + 1] : w[2 * q];
      const float send = b2 ? w[2 * q] : w[2 * q + 1];
      u2[q] = keep + __shfl_xor(send, 2, 64);
    }
    // bit 2
    float f;
    {
      const float keep = b4 ? u2[1] : u2[0];
      const float send = b4 ? u2[0] : u2[1];
      f = keep + __shfl_xor(send, 4, 64);
    }
    // pure reduction across 8-lane groups; lane l now holds pair (l&7)
    f += __shfl_xor(f, 8, 64);
    f += __shfl_xor(f, 16, 64);
    f += __shfl_xor(f, 32, 64);
    if (lane < 8) op[pb + lane] = f;
  }
}

// ---- fallback (tiny workspace): direct fp32, slow but correct ----
__global__ __launch_bounds__(256) void naive_k(const float* __restrict__ emb,
                                               const int* __restrict__ index,
                                               const float* __restrict__ W,
                                               const float* __restrict__ wl,
                                               float* __restrict__ out) {
  __shared__ float bs[FD];
  __shared__ float red[256];
  const int c = blockIdx.y, p = blockIdx.x;
  const int i0 = index[((size_t)c * NPAIRS + p) * 2];
  const int i1 = index[((size_t)c * NPAIRS + p) * 2 + 1];
  const float* wlc = wl + (size_t)c * FD;
  for (int k = threadIdx.x; k < FD; k += 256) bs[k] = emb[(size_t)i1 * FD + k] * wlc[k];
  __syncthreads();
  float s = 0.f;
  for (int n = threadIdx.x; n < FD; n += 256) {
    const float* wr = W + (size_t)n * FD;
    float tacc = 0.f;
    for (int k = 0; k < FD; k++) tacc += wr[k] * bs[k];
    s += tacc * emb[(size_t)i0 * FD + n] * wlc[n];
  }
  red[threadIdx.x] = s;
  __syncthreads();
  for (int st = 128; st > 0; st >>= 1) {
    if (threadIdx.x < st) red[threadIdx.x] += red[threadIdx.x + st];
    __syncthreads();
  }
  if (threadIdx.x == 0) out[(size_t)c * NPAIRS + p] = red[0];
}

extern "C" void kernel_launch(void* const* d_in, const int* in_sizes, int n_in,
                              void* d_out, int out_size, void* d_ws, size_t ws_size,
                              hipStream_t stream) {
  const float* emb = (const float*)d_in[0];
  const int* index = (const int*)d_in[1];
  const float* Wg = (const float*)d_in[2];
  const float* wl = (const float*)d_in[3];
  float* out = (float*)d_out;

  const size_t ebytes = (size_t)NE * FD * 2;  // 4 MiB bf16 embedding
  const size_t wtcell = (size_t)FD * FD * 2;  // 0.5 MiB per-cell Wt
  const size_t ucell = (size_t)NE * FD * 2;   // 4 MiB per-cell U
  size_t avail = ws_size > ebytes ? ws_size - ebytes : 0;
  int G = (int)(avail / (wtcell + ucell));
  if (G > NCELLS) G = NCELLS;

  if (G < 1) {
    naive_k<<<dim3(NPAIRS, NCELLS), 256, 0, stream>>>(emb, index, Wg, wl, out);
    return;
  }

  unsigned short* Ebf = (unsigned short*)d_ws;
  unsigned short* Wt = (unsigned short*)((char*)d_ws + ebytes);
  unsigned short* U = (unsigned short*)((char*)d_ws + ebytes + (size_t)G * wtcell);

  conv_e<<<dim3((NE * FD / 4) / 256), 256, 0, stream>>>(emb, Ebf);
  for (int c0 = 0; c0 < NCELLS; c0 += G) {
    int g = (NCELLS - c0 < G) ? (NCELLS - c0) : G;
    prep_w<<<dim3(FD / 32, FD / 32, g), 256, 0, stream>>>(Wg, wl, Wt, c0);
    // grid = 16 row-blocks x 2 col-blocks x g cells, flattened (nwg % 8 == 0)
    gemm_k<<<dim3(32 * g), 512, 0, stream>>>(Ebf, Wt, U);
    dot_k<<<dim3(NPAIRS / 128, g), 256, 0, stream>>>(U, Ebf, index, out, c0);
  }
}

// Round 2
// 240.498 us; speedup vs baseline: 1.0341x; 1.0111x over previous
//
#include <hip/hip_runtime.h>
#include <stdint.h>

#define NE 4096
#define FD 512
#define NCELLS 39
#define NPAIRS 8192
#define NT (FD / 64)  // 8 K-tiles of BK=64

typedef __attribute__((ext_vector_type(8))) short short8;
typedef __attribute__((ext_vector_type(8))) unsigned short ushort8;
typedef __attribute__((ext_vector_type(4))) float f32x4;
typedef __attribute__((ext_vector_type(4))) unsigned int uint4v;

__device__ __forceinline__ unsigned short f2bf(float f) {
  union { float f; uint32_t u; } v; v.f = f;
  uint32_t u = v.u;
  return (unsigned short)((u + 0x7fffu + ((u >> 16) & 1u)) >> 16);  // RNE
}
__device__ __forceinline__ float bf2f(unsigned short b) {
  return __uint_as_float(((uint32_t)b) << 16);
}

__device__ __forceinline__ void async16(const void* g, void* l) {
  __builtin_amdgcn_global_load_lds((const __attribute__((address_space(1))) void*)g,
                                   (__attribute__((address_space(3))) void*)l, 16, 0, 0);
}

// ---- kernel 1: embedding fp32 -> bf16 ----
__global__ __launch_bounds__(256) void conv_e(const float* __restrict__ E,
                                              unsigned short* __restrict__ Ebf) {
  const int i = blockIdx.x * 256 + threadIdx.x;
  const float4 v = ((const float4*)E)[i];
  ushort4 o;
  o.x = f2bf(v.x); o.y = f2bf(v.y); o.z = f2bf(v.z); o.w = f2bf(v.w);
  ((ushort4*)Ebf)[i] = o;
}

// ---- kernel 2: Wt[ci][k][n] = wl[c,n] * wl[c,k] * W[n,k], bf16, transposed ----
__global__ __launch_bounds__(256) void prep_w(const float* __restrict__ W,
                                              const float* __restrict__ wl,
                                              unsigned short* __restrict__ Wt,
                                              int c0) {
  __shared__ float tile[32][33];
  const int ci = blockIdx.z;
  const int tn = blockIdx.x * 32, tk = blockIdx.y * 32;
  const int tx = threadIdx.x & 31, ty = threadIdx.x >> 5;
  const float* wlr = wl + (size_t)(c0 + ci) * FD;
#pragma unroll
  for (int i = 0; i < 4; i++) {
    int n = tn + ty + i * 8;
    tile[ty + i * 8][tx] = W[(size_t)n * FD + tk + tx] * wlr[n];
  }
  __syncthreads();
  unsigned short* dst = Wt + (size_t)ci * FD * FD;
#pragma unroll
  for (int i = 0; i < 4; i++) {
    int kout = tk + ty + i * 8;
    dst[(size_t)kout * FD + tn + tx] = f2bf(tile[tx][ty + i * 8] * wlr[kout]);
  }
}

// ---- kernel 3: U[ci][e][k] = sum_n Ebf[e,n] * Wt[ci][k][n]  (bf16 out) ----
// 256x256 8-phase template; block->XCD mapping gives each XCD a FIXED pair of
// A-row panels (512KB, stays L2-resident all dispatch) and streams (ci,by)
// B-panels through it.  A fetch: ~300MB -> 4MB total; B: fetched once/XCD.
// This attacks the measured L2-thrash (800MB TCC traffic @ 6.8 TB/s, r1).
__global__ __launch_bounds__(512, 2) void gemm_k(const unsigned short* __restrict__ Ebf,
                                                 const unsigned short* __restrict__ Wt,
                                                 unsigned short* __restrict__ U) {
  __shared__ unsigned short lds[2][2][2][128 * 64];  // [buf][A=0/B=1][half][row*64+col]
  const int t = threadIdx.x;
  const int id = blockIdx.x;
  // HW round-robins consecutive blockIdx across the 8 XCDs: id&7 = XCD.
  // Per-XCD chunk of 4*g blocks: bx fixed to {2*xcd, 2*xcd+1}; (bxh,by) innermost
  // in time so each B panel is fetched just-in-time and used by both bx blocks.
  const int xcd = id & 7;
  const int j = id >> 3;            // 0 .. 4*g-1
  const int bxh = j & 1;
  const int by = (j >> 1) & 1;      // 2 col-blocks of 256 k
  const int ci = j >> 2;            // cell
  const int bx = xcd * 2 + bxh;     // 16 row-blocks of 256 entities

  const unsigned short* Ag = Ebf + (size_t)bx * 256 * FD;
  const unsigned short* Bg = Wt + (size_t)ci * FD * FD + (size_t)by * 256 * FD;

  const int wave = t >> 6, lane = t & 63;
  const int wm = wave >> 2, wn = wave & 3;  // 2M x 4N wave grid
  const int lr = lane & 15, lq = lane >> 4;

  // staging: physical granule pg (row=pg>>3, g=pg&7); source uses g ^ (row&7)
  const int pg0 = t, pg1 = 512 + t;
  const int sr0 = pg0 >> 3, sg0 = pg0 & 7;
  const int sr1 = pg1 >> 3, sg1 = pg1 & 7;
  const int soff0 = sr0 * FD + ((sg0 ^ (sr0 & 7)) << 3);
  const int soff1 = sr1 * FD + ((sg1 ^ (sr1 & 7)) << 3);
  const int loff0 = pg0 * 8, loff1 = pg1 * 8;

  // read swizzle: frag rows always have row%8 == lr%8
  const int swz0 = (lq ^ (lr & 7)) << 3;        // k-slice 0 granule
  const int swz1 = ((4 + lq) ^ (lr & 7)) << 3;  // k-slice 1 granule

#define STAGE(OP, HALF, KT, GBASE)                                                \
  do {                                                                            \
    const int bi_ = (KT) & 1;             /* buffer from UNclamped kt */          \
    const int kt_ = (KT) < NT ? (KT) : (NT - 1); /* clamp src, keep count */      \
    const unsigned short* gb_ = (GBASE) + (size_t)(HALF) * (128 * FD) + kt_ * 64; \
    unsigned short* d_ = &lds[bi_][OP][HALF][0];                                  \
    async16(gb_ + soff0, d_ + loff0);                                             \
    async16(gb_ + soff1, d_ + loff1);                                             \
  } while (0)

  short8 a[8], b01[4], b23[4];
  f32x4 acc[8][4];
#pragma unroll
  for (int i = 0; i < 8; i++)
#pragma unroll
    for (int j2 = 0; j2 < 4; j2++) acc[i][j2] = (f32x4){0.f, 0.f, 0.f, 0.f};

#define LDA(BUF, MSET)                                                  \
  do {                                                                  \
    const unsigned short* p_ = &lds[BUF][0][wm][0];                     \
    _Pragma("unroll") for (int mi_ = 0; mi_ < 4; ++mi_) {               \
      const int row_ = (MSET) * 64 + mi_ * 16 + lr;                     \
      a[mi_ * 2 + 0] = *(const short8*)&p_[row_ * 64 + swz0];           \
      a[mi_ * 2 + 1] = *(const short8*)&p_[row_ * 64 + swz1];           \
    }                                                                   \
  } while (0)

#define LDB(BUF, NSET, DST)                                             \
  do {                                                                  \
    const unsigned short* p_ = &lds[BUF][1][wn >> 1][0];                \
    _Pragma("unroll") for (int ni_ = 0; ni_ < 2; ++ni_) {               \
      const int row_ = (wn & 1) * 64 + ((NSET) * 2 + ni_) * 16 + lr;    \
      (DST)[ni_ * 2 + 0] = *(const short8*)&p_[row_ * 64 + swz0];       \
      (DST)[ni_ * 2 + 1] = *(const short8*)&p_[row_ * 64 + swz1];       \
    }                                                                   \
  } while (0)

#define MMA(MSET, NSET, B)                                                               \
  do {                                                                                   \
    __builtin_amdgcn_s_setprio(1);                                                       \
    _Pragma("unroll") for (int mi_ = 0; mi_ < 4; ++mi_)                                  \
    _Pragma("unroll") for (int ni_ = 0; ni_ < 2; ++ni_)                                  \
    _Pragma("unroll") for (int s_ = 0; s_ < 2; ++s_)                                     \
      acc[(MSET) * 4 + mi_][(NSET) * 2 + ni_] = __builtin_amdgcn_mfma_f32_16x16x32_bf16( \
          a[mi_ * 2 + s_], (B)[ni_ * 2 + s_],                                            \
          acc[(MSET) * 4 + mi_][(NSET) * 2 + ni_], 0, 0, 0);                             \
    __builtin_amdgcn_s_setprio(0);                                                       \
  } while (0)

#define SYNC_LG()                                        \
  do {                                                   \
    __builtin_amdgcn_s_barrier();                        \
    asm volatile("s_waitcnt lgkmcnt(0)" ::: "memory");   \
  } while (0)

  // prologue: all 4 half-tiles of kt0 + B-lo,A-lo of kt1 (6 HTs = 12 loads)
  STAGE(1, 0, 0, Bg); STAGE(0, 0, 0, Ag); STAGE(1, 1, 0, Bg); STAGE(0, 1, 0, Ag);
  STAGE(1, 0, 1, Bg); STAGE(0, 0, 1, Ag);
  asm volatile("s_waitcnt vmcnt(4)" ::: "memory");  // kt0 fully landed
  __builtin_amdgcn_s_barrier();

  for (int it = 0; it < NT / 2; ++it) {
    const int k1 = 2 * it + 1, k2 = 2 * it + 2, k3 = 2 * it + 3;
    // ----- K-tile 2it from buf0 -----
    // ph1: Q(m0-3,n01); reads A03+Bn01 (12); stage B-hi(k1)->buf1
    LDA(0, 0); LDB(0, 0, b01);
    STAGE(1, 1, k1, Bg);
    SYNC_LG(); MMA(0, 0, b01); __builtin_amdgcn_s_barrier();
    // ph2: Q(m0-3,n23); reads Bn23 (4); stage A-hi(k1)->buf1
    LDB(0, 1, b23);
    STAGE(0, 1, k1, Ag);
    SYNC_LG(); MMA(0, 1, b23); __builtin_amdgcn_s_barrier();
    // ph3: Q(m4-7,n23); reads A47 (8); stage B-lo(k2)->buf0 (B reads of buf0 done ph2)
    LDA(0, 1);
    STAGE(1, 0, k2, Bg);
    SYNC_LG(); MMA(1, 1, b23); __builtin_amdgcn_s_barrier();
    // ph4: Q(m4-7,n01); no reads; stage A-lo(k2)->buf0 (A reads done ph3); counted vmcnt
    STAGE(0, 0, k2, Ag);
    __builtin_amdgcn_s_barrier();
    MMA(1, 0, b01);
    asm volatile("s_waitcnt vmcnt(4)" ::: "memory");  // kt1 fully landed
    __builtin_amdgcn_s_barrier();
    // ----- K-tile 2it+1 from buf1 -----
    // ph5: stage B-hi(k2)->buf0
    LDA(1, 0); LDB(1, 0, b01);
    STAGE(1, 1, k2, Bg);
    SYNC_LG(); MMA(0, 0, b01); __builtin_amdgcn_s_barrier();
    // ph6: stage A-hi(k2)->buf0
    LDB(1, 1, b23);
    STAGE(0, 1, k2, Ag);
    SYNC_LG(); MMA(0, 1, b23); __builtin_amdgcn_s_barrier();
    // ph7: stage B-lo(k3)->buf1 (B reads of buf1 done ph6)
    LDA(1, 1);
    STAGE(1, 0, k3, Bg);
    SYNC_LG(); MMA(1, 1, b23); __builtin_amdgcn_s_barrier();
    // ph8: stage A-lo(k3)->buf1 (A reads done ph7); counted vmcnt
    STAGE(0, 0, k3, Ag);
    __builtin_amdgcn_s_barrier();
    MMA(1, 0, b01);
    asm volatile("s_waitcnt vmcnt(4)" ::: "memory");  // kt2 fully landed
    __builtin_amdgcn_s_barrier();
  }

  // epilogue: C/D layout col=lane&15, row=(lane>>4)*4+reg
  unsigned short* Up = U + (size_t)ci * NE * FD;
  const int mrow0 = bx * 256 + wm * 128;
  const int ncol0 = by * 256 + wn * 64;
#pragma unroll
  for (int mi = 0; mi < 8; ++mi) {
    const int mbase = mrow0 + mi * 16 + lq * 4;
#pragma unroll
    for (int ni = 0; ni < 4; ++ni) {
      const int n = ncol0 + ni * 16 + lr;
#pragma unroll
      for (int r = 0; r < 4; ++r)
        Up[(size_t)(mbase + r) * FD + n] = f2bf(acc[mi][ni][r]);
    }
  }
#undef STAGE
#undef LDA
#undef LDB
#undef MMA
#undef SYNC_LG
}

// ---- kernel 4: out[c,p] = sum_k U[ci,i0,k] * Ebf[i1,k] ----
// Transpose-butterfly reduce: 10 shuffles per 8-pair batch, identical tree.
__global__ __launch_bounds__(256) void dot_k(const unsigned short* __restrict__ U,
                                             const unsigned short* __restrict__ Ebf,
                                             const int* __restrict__ index,
                                             float* __restrict__ out,
                                             int c0) {
  const int ci = blockIdx.y;
  const int c = c0 + ci;
  const int wave = threadIdx.x >> 6, lane = threadIdx.x & 63;
  const unsigned short* Uc = U + (size_t)ci * NE * FD;
  const size_t cp = (size_t)c * NPAIRS;
  const int2* idx2 = (const int2*)index + cp;
  float* op = out + cp;
  const int pbase = (blockIdx.x * 4 + wave) * 32;

  const int b1 = lane & 1, b2 = (lane >> 1) & 1, b4 = (lane >> 2) & 1;

  for (int batch = 0; batch < 4; batch++) {
    const int pb = pbase + batch * 8;
    int2 id[8];
#pragma unroll
    for (int b = 0; b < 8; b++) id[b] = idx2[pb + b];
    uint4v uv[8], ev[8];
#pragma unroll
    for (int b = 0; b < 8; b++) {
      uv[b] = *(const uint4v*)(Uc + (size_t)id[b].x * FD + lane * 8);
      ev[b] = *(const uint4v*)(Ebf + (size_t)id[b].y * FD + lane * 8);
    }
    float v[8];
#pragma unroll
    for (int b = 0; b < 8; b++) {
      const ushort8 u = *(const ushort8*)&uv[b];
      const ushort8 e = *(const ushort8*)&ev[b];
      float s = 0.f;
#pragma unroll
      for (int q = 0; q < 8; q++) s += bf2f(u[q]) * bf2f(e[q]);
      v[b] = s;
    }
    // fold pair-index bit 0 into lane bit 0
    float w[4];
#pragma unroll
    for (int q = 0; q < 4; q++) {
      const float keep = b1 ? v[2 * q + 1] : v[2 * q];
      const float send = b1 ? v[2 * q] : v[2 * q + 1];
      w[q] = keep + __shfl_xor(send, 1, 64);
    }
    // bit 1
    float u2[2];
#pragma unroll
    for (int q = 0; q < 2; q++) {
      const float keep = b2 ? w[2 * q + 1] : w[2 * q];
      const float send = b2 ? w[2 * q] : w[2 * q + 1];
      u2[q] = keep + __shfl_xor(send, 2, 64);
    }
    // bit 2
    float f;
    {
      const float keep = b4 ? u2[1] : u2[0];
      const float send = b4 ? u2[0] : u2[1];
      f = keep + __shfl_xor(send, 4, 64);
    }
    // pure reduction across 8-lane groups; lane l now holds pair (l&7)
    f += __shfl_xor(f, 8, 64);
    f += __shfl_xor(f, 16, 64);
    f += __shfl_xor(f, 32, 64);
    if (lane < 8) op[pb + lane] = f;
  }
}

// ---- fallback (tiny workspace): direct fp32, slow but correct ----
__global__ __launch_bounds__(256) void naive_k(const float* __restrict__ emb,
                                               const int* __restrict__ index,
                                               const float* __restrict__ W,
                                               const float* __restrict__ wl,
                                               float* __restrict__ out) {
  __shared__ float bs[FD];
  __shared__ float red[256];
  const int c = blockIdx.y, p = blockIdx.x;
  const int i0 = index[((size_t)c * NPAIRS + p) * 2];
  const int i1 = index[((size_t)c * NPAIRS + p) * 2 + 1];
  const float* wlc = wl + (size_t)c * FD;
  for (int k = threadIdx.x; k < FD; k += 256) bs[k] = emb[(size_t)i1 * FD + k] * wlc[k];
  __syncthreads();
  float s = 0.f;
  for (int n = threadIdx.x; n < FD; n += 256) {
    const float* wr = W + (size_t)n * FD;
    float tacc = 0.f;
    for (int k = 0; k < FD; k++) tacc += wr[k] * bs[k];
    s += tacc * emb[(size_t)i0 * FD + n] * wlc[n];
  }
  red[threadIdx.x] = s;
  __syncthreads();
  for (int st = 128; st > 0; st >>= 1) {
    if (threadIdx.x < st) red[threadIdx.x] += red[threadIdx.x + st];
    __syncthreads();
  }
  if (threadIdx.x == 0) out[(size_t)c * NPAIRS + p] = red[0];
}

extern "C" void kernel_launch(void* const* d_in, const int* in_sizes, int n_in,
                              void* d_out, int out_size, void* d_ws, size_t ws_size,
                              hipStream_t stream) {
  const float* emb = (const float*)d_in[0];
  const int* index = (const int*)d_in[1];
  const float* Wg = (const float*)d_in[2];
  const float* wl = (const float*)d_in[3];
  float* out = (float*)d_out;

  const size_t ebytes = (size_t)NE * FD * 2;  // 4 MiB bf16 embedding
  const size_t wtcell = (size_t)FD * FD * 2;  // 0.5 MiB per-cell Wt
  const size_t ucell = (size_t)NE * FD * 2;   // 4 MiB per-cell U
  size_t avail = ws_size > ebytes ? ws_size - ebytes : 0;
  int G = (int)(avail / (wtcell + ucell));
  if (G > NCELLS) G = NCELLS;

  if (G < 1) {
    naive_k<<<dim3(NPAIRS, NCELLS), 256, 0, stream>>>(emb, index, Wg, wl, out);
    return;
  }

  unsigned short* Ebf = (unsigned short*)d_ws;
  unsigned short* Wt = (unsigned short*)((char*)d_ws + ebytes);
  unsigned short* U = (unsigned short*)((char*)d_ws + ebytes + (size_t)G * wtcell);

  conv_e<<<dim3((NE * FD / 4) / 256), 256, 0, stream>>>(emb, Ebf);
  for (int c0 = 0; c0 < NCELLS; c0 += G) {
    int g = (NCELLS - c0 < G) ? (NCELLS - c0) : G;
    prep_w<<<dim3(FD / 32, FD / 32, g), 256, 0, stream>>>(Wg, wl, Wt, c0);
    // grid = 16 row-blocks x 2 col-blocks x g cells; id&7 = XCD, bx pinned per XCD
    gemm_k<<<dim3(32 * g), 512, 0, stream>>>(Ebf, Wt, U);
    dot_k<<<dim3(NPAIRS / 128, g), 256, 0, stream>>>(U, Ebf, index, out, c0);
  }
}